// Round 6
// baseline (521.526 us; speedup 1.0000x reference)
//
#include <hip/hip_runtime.h>
#include <math.h>

#define SEQL 256
#define DM   256
#define NH   8
#define DKH  32
#define BSZ  4
#define NKN  16
#define LSTR 264   // u16 LDS row stride (528 B)

// ---------------- wave (64-lane) helpers ----------------
__device__ __forceinline__ float wave_red_sum(float v) {
#pragma unroll
  for (int o = 32; o > 0; o >>= 1) v += __shfl_xor(v, o);
  return v;
}
__device__ __forceinline__ float wave_red_max(float v) {
#pragma unroll
  for (int o = 32; o > 0; o >>= 1) v = fmaxf(v, __shfl_xor(v, o));
  return v;
}
__device__ __forceinline__ float wave_incl_scan(float v) {
  const int lane = threadIdx.x & 63;
#pragma unroll
  for (int o = 1; o < 64; o <<= 1) {
    float u = __shfl_up(v, o);
    if (lane >= o) v += u;
  }
  return v;
}

// ---------------- bf16 helpers (bf16 = high 16 bits of f32, RNE pack) ----------------
__device__ __forceinline__ unsigned short bf16r(float f) {
  unsigned u = __float_as_uint(f);
  u = (u + 0x7fffu + ((u >> 16) & 1u)) >> 16;
  return (unsigned short)u;
}
__device__ __forceinline__ unsigned pack_bf16x2(float a, float b) {  // lo=a, hi=b
  return (unsigned)bf16r(a) | ((unsigned)bf16r(b) << 16);
}

// ---------------- shared PV core: acc[4r][4c] += P[32? rows][256j] * V^T ----------------
// Pl: [32][LSTR] u16 (row=i-local, col=j, bf16); Vt: [32][LSTR] u16 (row=c, col=j)
// thread: r0=tid>>5 (4 rows), cg=tid&7 (4 cols), jq=(tid>>3)&3 (j-quarter, stride-32 interleave)
__device__ __forceinline__ void pv_core(const unsigned short (*Pl)[LSTR],
                                        const unsigned short (*Vt)[LSTR],
                                        int tid, float acc[4][4]) {
  const int r0 = tid >> 5, cg = tid & 7, jq = (tid >> 3) & 3;
#pragma unroll
  for (int t = 0; t < 8; ++t) {
    const int j0 = t * 32 + jq * 8;
    uint4 pu[4], vu[4];
#pragma unroll
    for (int r = 0; r < 4; ++r) pu[r] = *reinterpret_cast<const uint4*>(&Pl[r0 * 4 + r][j0]);
#pragma unroll
    for (int c = 0; c < 4; ++c) vu[c] = *reinterpret_cast<const uint4*>(&Vt[cg * 4 + c][j0]);
#pragma unroll
    for (int d = 0; d < 4; ++d) {
      float pl[4], ph[4], vl[4], vh[4];
#pragma unroll
      for (int r = 0; r < 4; ++r) {
        const unsigned w = (&pu[r].x)[d];
        pl[r] = __uint_as_float(w << 16);
        ph[r] = __uint_as_float(w & 0xffff0000u);
      }
#pragma unroll
      for (int c = 0; c < 4; ++c) {
        const unsigned w = (&vu[c].x)[d];
        vl[c] = __uint_as_float(w << 16);
        vh[c] = __uint_as_float(w & 0xffff0000u);
      }
#pragma unroll
      for (int r = 0; r < 4; ++r)
#pragma unroll
        for (int c = 0; c < 4; ++c)
          acc[r][c] = fmaf(ph[r], vh[c], fmaf(pl[r], vl[c], acc[r][c]));
    }
  }
}
__device__ __forceinline__ void pv_reduce_jq(int tid, float acc[4][4]) {
#pragma unroll
  for (int r = 0; r < 4; ++r)
#pragma unroll
    for (int c = 0; c < 4; ++c) {
      float v = acc[r][c];
      v += __shfl_xor(v, 8);
      v += __shfl_xor(v, 16);
      acc[r][c] = v;
    }
}

// ---------------- multi-set GEMM 64x64: C[M,256] = A[M,256] @ W + bias ----------------
struct GemmSet { const float* A; const float* W; const float* bias; float* C; int M; };
struct Gemm4 { GemmSet s[4]; };

__global__ __launch_bounds__(256) void dt_gemmN(Gemm4 args) {
  const GemmSet g = args.s[blockIdx.z];
  const int bm = blockIdx.x * 64, bn = blockIdx.y * 64;
  if (bm >= g.M) return;
  __shared__ float As[16][68];
  __shared__ float Bs[16][68];
  const int tid = threadIdx.x;
  const int tc = tid & 15, tr = tid >> 4;
  float acc[4][4] = {};
  for (int k0 = 0; k0 < DM; k0 += 16) {
    {
      const int m = tid >> 2, kq = tid & 3;
      int row = bm + m; row = row < g.M ? row : (g.M - 1);
      const float4 v = *reinterpret_cast<const float4*>(&g.A[(size_t)row * DM + k0 + kq * 4]);
      As[kq * 4 + 0][m] = v.x; As[kq * 4 + 1][m] = v.y;
      As[kq * 4 + 2][m] = v.z; As[kq * 4 + 3][m] = v.w;
    }
    {
      const int k = tid >> 4, nq = tid & 15;
      const float4 v = *reinterpret_cast<const float4*>(&g.W[(size_t)(k0 + k) * DM + bn + nq * 4]);
      *reinterpret_cast<float4*>(&Bs[k][nq * 4]) = v;
    }
    __syncthreads();
#pragma unroll
    for (int k = 0; k < 16; ++k) {
      float a[4], b[4];
#pragma unroll
      for (int i = 0; i < 4; ++i) a[i] = As[k][tr * 4 + i];
#pragma unroll
      for (int j = 0; j < 4; ++j) b[j] = Bs[k][tc * 4 + j];
#pragma unroll
      for (int i = 0; i < 4; ++i)
#pragma unroll
        for (int j = 0; j < 4; ++j) acc[i][j] = fmaf(a[i], b[j], acc[i][j]);
    }
    __syncthreads();
  }
#pragma unroll
  for (int i = 0; i < 4; ++i) {
    const int row = bm + tr * 4 + i;
    if (row >= g.M) continue;
    float4 o;
    o.x = acc[i][0] + g.bias[bn + tc * 4 + 0];
    o.y = acc[i][1] + g.bias[bn + tc * 4 + 1];
    o.z = acc[i][2] + g.bias[bn + tc * 4 + 2];
    o.w = acc[i][3] + g.bias[bn + tc * 4 + 3];
    *reinterpret_cast<float4*>(&g.C[(size_t)row * DM + bn + tc * 4]) = o;
  }
}

// ---------------- multi-set GEMM 32x64 (M must be multiple of 32) ----------------
__global__ __launch_bounds__(256) void dt_gemm32(Gemm4 args) {
  const GemmSet g = args.s[blockIdx.z];
  const int bm = blockIdx.x * 32, bn = blockIdx.y * 64;
  __shared__ float As[16][36];
  __shared__ float Bs[16][68];
  const int tid = threadIdx.x;
  const int tc = tid & 15, tr = tid >> 4;
  float acc[2][4] = {};
  for (int k0 = 0; k0 < DM; k0 += 16) {
    if (tid < 128) {
      const int m = tid >> 2, kq = tid & 3;
      const float4 v = *reinterpret_cast<const float4*>(&g.A[(size_t)(bm + m) * DM + k0 + kq * 4]);
      As[kq * 4 + 0][m] = v.x; As[kq * 4 + 1][m] = v.y;
      As[kq * 4 + 2][m] = v.z; As[kq * 4 + 3][m] = v.w;
    }
    {
      const int k = tid >> 4, nq = tid & 15;
      const float4 v = *reinterpret_cast<const float4*>(&g.W[(size_t)(k0 + k) * DM + bn + nq * 4]);
      *reinterpret_cast<float4*>(&Bs[k][nq * 4]) = v;
    }
    __syncthreads();
#pragma unroll
    for (int k = 0; k < 16; ++k) {
      float a[2], b[4];
      a[0] = As[k][tr * 2 + 0];
      a[1] = As[k][tr * 2 + 1];
#pragma unroll
      for (int j = 0; j < 4; ++j) b[j] = Bs[k][tc * 4 + j];
#pragma unroll
      for (int i = 0; i < 2; ++i)
#pragma unroll
        for (int j = 0; j < 4; ++j) acc[i][j] = fmaf(a[i], b[j], acc[i][j]);
    }
    __syncthreads();
  }
#pragma unroll
  for (int i = 0; i < 2; ++i) {
    const int row = bm + tr * 2 + i;
    float4 o;
    o.x = acc[i][0] + g.bias[bn + tc * 4 + 0];
    o.y = acc[i][1] + g.bias[bn + tc * 4 + 1];
    o.z = acc[i][2] + g.bias[bn + tc * 4 + 2];
    o.w = acc[i][3] + g.bias[bn + tc * 4 + 3];
    *reinterpret_cast<float4*>(&g.C[(size_t)row * DM + bn + tc * 4]) = o;
  }
}

// ---------------- blocks 1-3 scores (2-set), 32x32 tiles ----------------
__global__ __launch_bounds__(256) void dt_scores_nt2(const float* __restrict__ Q0,
                                                     const float* __restrict__ Q1,
                                                     float* __restrict__ Sa,
                                                     float* __restrict__ Sb) {
  const int z = blockIdx.z;
  const int set = z >> 5, bh = z & 31;
  const float* Qp = set ? Q1 : Q0;
  float* S = set ? Sb : Sa;
  const int b = bh >> 3, h = bh & 7;
  const float* Q = Qp + (size_t)b * SEQL * DM + h * DKH;
  __shared__ float Qs[32][33], Ks[32][33];
  const int tid = threadIdx.x;
  const int i0 = blockIdx.x * 32, j0 = blockIdx.y * 32;
  {
    const int r = tid >> 3, gq = (tid & 7) * 4;
    const float4 q = *reinterpret_cast<const float4*>(&Q[(size_t)(i0 + r) * DM + gq]);
    Qs[r][gq + 0] = q.x; Qs[r][gq + 1] = q.y; Qs[r][gq + 2] = q.z; Qs[r][gq + 3] = q.w;
    const float4 k = *reinterpret_cast<const float4*>(&Q[(size_t)(j0 + r) * DM + gq]);
    Ks[r][gq + 0] = k.x; Ks[r][gq + 1] = k.y; Ks[r][gq + 2] = k.z; Ks[r][gq + 3] = k.w;
  }
  __syncthreads();
  const int tj = tid & 31, tig = tid >> 5;
  float acc[4] = {0.f, 0.f, 0.f, 0.f};
#pragma unroll
  for (int k = 0; k < DKH; ++k) {
    const float bk = Ks[tj][k];
#pragma unroll
    for (int r = 0; r < 4; ++r) acc[r] = fmaf(Qs[tig * 4 + r][k], bk, acc[r]);
  }
#pragma unroll
  for (int r = 0; r < 4; ++r)
    S[((size_t)bh * SEQL + i0 + tig * 4 + r) * SEQL + j0 + tj] = acc[r] * 0.17677669529663687f;
}

// ---------------- block 4 base scores (i-independent) ----------------
__global__ __launch_bounds__(256) void dt_scores4(const float* __restrict__ Q4h,
                                                  const float* __restrict__ Kp,
                                                  float* __restrict__ S0) {
  const int idx = blockIdx.x * 256 + threadIdx.x;  // ((b*16+nk)*8+h)*256 + j
  const int j = idx & 255;
  const int h = (idx >> 8) & 7;
  const int nk = (idx >> 11) & 15;
  const int b = idx >> 15;
  const float* q = Q4h + nk * DM + h * DKH;
  const float* k = Kp + ((size_t)(b * SEQL + j)) * DM + h * DKH;
  float acc = 0.f;
#pragma unroll
  for (int c = 0; c < DKH; ++c) acc = fmaf(q[c], k[c], acc);
  S0[idx] = acc * 0.17677669529663687f;
}

// ---------------- block 4 prefix precompute ----------------
__global__ __launch_bounds__(256) void dt_prep4(const float* __restrict__ S0,
                                                float* __restrict__ Pfx) {
  const int wid = threadIdx.x >> 6, lane = threadIdx.x & 63;
  const int row = blockIdx.x * 4 + wid;
  const float4 s4 = *reinterpret_cast<const float4*>(S0 + (size_t)row * SEQL + lane * 4);
  float s[4] = {s4.x, s4.y, s4.z, s4.w};
  float mx = fmaxf(fmaxf(s[0], s[1]), fmaxf(s[2], s[3]));
  mx = wave_red_max(mx);
  float e[4], t = 0.f;
#pragma unroll
  for (int q = 0; q < 4; ++q) { e[q] = __expf(s[q] - mx); t += e[q]; }
  const float incl = wave_incl_scan(t);
  float run = incl - t;
  float4 o;
  run += e[0]; o.x = run;
  run += e[1]; o.y = run;
  run += e[2]; o.z = run;
  run += e[3]; o.w = run;
  *reinterpret_cast<float4*>(Pfx + (size_t)row * SEQL + lane * 4) = o;
}

// ---------------- decay-softmax blocks 1-3 (2-set), wave-per-row ----------------
__global__ __launch_bounds__(256) void dt_softmax13w2(const float* __restrict__ Sa,
                                                      const float* __restrict__ Sb,
                                                      float* __restrict__ Pa,
                                                      float* __restrict__ Pb,
                                                      const float* __restrict__ g0,
                                                      const float* __restrict__ g1) {
  const int wid = threadIdx.x >> 6, lane = threadIdx.x & 63;
  const int grow = blockIdx.x * 4 + wid;
  const int set = grow >> 13;
  const int row = grow & 8191;
  const float* S = set ? Sb : Sa;
  float* P = set ? Pb : Pa;
  const float* gam = set ? g1 : g0;
  const int i = row & 255, h = (row >> 8) & 7;
  const float g = -fabsf(gam[h]);
  const int jb = lane * 4;
  const float4 s4 = *reinterpret_cast<const float4*>(S + (size_t)row * SEQL + jb);
  float s[4] = {s4.x, s4.y, s4.z, s4.w};
  float mx = -1e30f;
#pragma unroll
  for (int q = 0; q < 4; ++q) if (jb + q <= i) mx = fmaxf(mx, s[q]);
  mx = wave_red_max(mx);
  float e[4], t = 0.f;
#pragma unroll
  for (int q = 0; q < 4; ++q) { e[q] = (jb + q <= i) ? __expf(s[q] - mx) : 0.f; t += e[q]; }
  const float incl = wave_incl_scan(t);
  const float total = __shfl(incl, 63);
  const float inv = 1.f / total;
  float run = incl - t;
  float p2[4], t2 = 0.f;
#pragma unroll
  for (int q = 0; q < 4; ++q) {
    run += e[q];
    const float cum = run * inv;
    float dd = (1.f - cum) * (float)(i - jb - q);
    dd = dd > 0.f ? dd : 0.f;
    float eff = __expf(g * sqrtf(dd));
    eff = fmaxf(eff, 1e-5f);
    const float y = s[q] * eff;
    p2[q] = (jb + q <= i) ? __expf(y) : 0.f;
    t2 += p2[q];
  }
  const float sum2 = wave_red_sum(t2);
  const float inv2 = 1.f / sum2;
  float4 o = {p2[0] * inv2, p2[1] * inv2, p2[2] * inv2, p2[3] * inv2};
  *reinterpret_cast<float4*>(P + (size_t)row * SEQL + jb) = o;
}

// ---------------- fused decay-softmax + PV, block 4 (bf16 LDS, 4 chunks/block) ----------------
// grid (2, 512): blockIdx.y = (b*16+nk)*8+h, blockIdx.x picks 4 of 8 i-chunks
__global__ __launch_bounds__(256, 4) void dt_sm_pv4(const float* __restrict__ S0,
                                                    const float* __restrict__ Pfx,
                                                    const float* __restrict__ Vp,
                                                    const float* __restrict__ gam,
                                                    float* __restrict__ KS,
                                                    float* __restrict__ O) {
  __shared__ unsigned short Vt[32][LSTR];   // V^T: [c][j] bf16
  __shared__ unsigned short Pl[32][LSTR];   // P rows of one 32-i chunk, bf16
  __shared__ float Pfl[256];                // prefix row (fp32)
  const int z = blockIdx.y;                 // (b*16+nk)*8+h
  const int h = z & 7, b = z >> 7;
  const int nk = (z >> 3) & 15, bnk = z >> 3;
  const int tid = threadIdx.x, lane = tid & 63, w = tid >> 6;
  const float* Vbase = Vp + (size_t)b * SEQL * DM + h * DKH;
  {
    const int jr = tid >> 3, gq = tid & 7;
#pragma unroll
    for (int t = 0; t < 8; ++t) {
      const int j = jr + t * 32;
      const float4 v = *reinterpret_cast<const float4*>(Vbase + (size_t)j * DM + gq * 4);
      Vt[gq * 4 + 0][j] = bf16r(v.x);
      Vt[gq * 4 + 1][j] = bf16r(v.y);
      Vt[gq * 4 + 2][j] = bf16r(v.z);
      Vt[gq * 4 + 3][j] = bf16r(v.w);
    }
  }
  if (tid < 64) {
    const float4 p = *reinterpret_cast<const float4*>(Pfx + (size_t)z * SEQL + tid * 4);
    *reinterpret_cast<float4*>(&Pfl[tid * 4]) = p;
  }
  const float4 s4 = *reinterpret_cast<const float4*>(S0 + (size_t)z * SEQL + lane * 4);
  const float4 p4 = *reinterpret_cast<const float4*>(Pfx + (size_t)z * SEQL + lane * 4);
  const float s[4] = {s4.x, s4.y, s4.z, s4.w};
  const float pj[4] = {p4.x, p4.y, p4.z, p4.w};
  const float g = -fabsf(gam[h]);
  const int jb = lane * 4;
  const int r0 = tid >> 5, cg = tid & 7;
  __syncthreads();

  for (int chunk = blockIdx.x * 4; chunk < blockIdx.x * 4 + 4; ++chunk) {
    const int i0 = chunk * 32;
#pragma unroll
    for (int r = 0; r < 8; ++r) {
      const int il = w * 8 + r;
      const int i = i0 + il;
      float pv[4];
      if (i == 0) {
        pv[0] = pv[1] = pv[2] = pv[3] = 0.f;
      } else {
        const float rinv = 1.f / Pfl[i - 1];
        float t = 0.f, m = 0.f;
#pragma unroll
        for (int q = 0; q < 4; ++q) {
          const float cum = pj[q] * rinv;
          float dd = (1.f - cum) * (float)(i - jb - q);
          dd = dd > 0.f ? dd : 0.f;
          float eff = __expf(g * sqrtf(dd));
          eff = fmaxf(eff, 1e-5f);
          const float y = s[q] * eff;
          pv[q] = (jb + q < i) ? __expf(y) : 0.f;
          t += pv[q];
          m = fmaxf(m, pv[q]);
        }
#pragma unroll
        for (int o = 32; o > 0; o >>= 1) {
          t += __shfl_xor(t, o);
          m = fmaxf(m, __shfl_xor(m, o));
        }
        const float inv2 = 1.f / t;
        const float scale = fminf(1.f / (m * inv2 + 1e-8f), 5.f);
        const float f = inv2 * scale;
        pv[0] *= f; pv[1] *= f; pv[2] *= f; pv[3] *= f;
      }
      const float4 o4 = {pv[0], pv[1], pv[2], pv[3]};
      *reinterpret_cast<float4*>(KS + ((((size_t)(b * NH + h)) * SEQL + i) * NKN + nk) * SEQL + jb) = o4;
      uint2 pk = {pack_bf16x2(pv[0], pv[1]), pack_bf16x2(pv[2], pv[3])};
      *reinterpret_cast<uint2*>(&Pl[il][jb]) = pk;
    }
    __syncthreads();
    float acc[4][4] = {};
    pv_core(Pl, Vt, tid, acc);
    pv_reduce_jq(tid, acc);
    if ((tid & 24) == 0) {
#pragma unroll
      for (int r = 0; r < 4; ++r) {
        const float4 oo = {acc[r][0], acc[r][1], acc[r][2], acc[r][3]};
        *reinterpret_cast<float4*>(O + ((size_t)(bnk * SEQL + i0 + r0 * 4 + r)) * DM + h * DKH + cg * 4) = oo;
      }
    }
    __syncthreads();  // Pl reused next chunk
  }
}

// ---------------- PV blocks 1-3 (2-set), bf16 LDS ----------------
__global__ __launch_bounds__(256, 4) void dt_pv13_2(const float* __restrict__ Pa,
                                                    const float* __restrict__ Pb,
                                                    const float* __restrict__ V0,
                                                    const float* __restrict__ V1,
                                                    float* __restrict__ Oa,
                                                    float* __restrict__ Ob) {
  __shared__ unsigned short Vt[32][LSTR];
  __shared__ unsigned short Pl[32][LSTR];
  const int z = blockIdx.y;
  const int set = z >> 5, bh = z & 31;
  const float* P = set ? Pb : Pa;
  const float* Vp = set ? V1 : V0;
  float* O = set ? Ob : Oa;
  const int b = bh >> 3, h = bh & 7;
  const int i0 = blockIdx.x * 32;
  const int tid = threadIdx.x;
  const float* Prow = P + ((size_t)bh * SEQL + i0) * SEQL;
  const float* Vbase = Vp + (size_t)b * SEQL * DM + h * DKH;
  {
    const int jr = tid >> 3, gq = tid & 7;
#pragma unroll
    for (int t = 0; t < 8; ++t) {
      const int j = jr + t * 32;
      const float4 v = *reinterpret_cast<const float4*>(Vbase + (size_t)j * DM + gq * 4);
      Vt[gq * 4 + 0][j] = bf16r(v.x);
      Vt[gq * 4 + 1][j] = bf16r(v.y);
      Vt[gq * 4 + 2][j] = bf16r(v.z);
      Vt[gq * 4 + 3][j] = bf16r(v.w);
    }
#pragma unroll
    for (int t = 0; t < 8; ++t) {
      const int id = t * 256 + tid;
      const int row = id >> 6, g4 = id & 63;
      const float4 p = *reinterpret_cast<const float4*>(Prow + (size_t)row * SEQL + g4 * 4);
      uint2 pk = {pack_bf16x2(p.x, p.y), pack_bf16x2(p.z, p.w)};
      *reinterpret_cast<uint2*>(&Pl[row][g4 * 4]) = pk;
    }
  }
  __syncthreads();
  float acc[4][4] = {};
  pv_core(Pl, Vt, tid, acc);
  pv_reduce_jq(tid, acc);
  const int r0 = tid >> 5, cg = tid & 7;
  if ((tid & 24) == 0) {
#pragma unroll
    for (int r = 0; r < 4; ++r) {
      const float4 oo = {acc[r][0], acc[r][1], acc[r][2], acc[r][3]};
      *reinterpret_cast<float4*>(O + ((size_t)(b * SEQL + i0 + r0 * 4 + r)) * DM + h * DKH + cg * 4) = oo;
    }
  }
}

// ---------------- residual + LayerNorm (2-set), wave-per-row ----------------
__global__ __launch_bounds__(256) void dt_ln_res2(const float* __restrict__ X0,
                                                  const float* __restrict__ X1,
                                                  const float* __restrict__ Y0,
                                                  const float* __restrict__ Y1,
                                                  const float* __restrict__ G0,
                                                  const float* __restrict__ G1,
                                                  const float* __restrict__ B0,
                                                  const float* __restrict__ B1,
                                                  float* __restrict__ Z0,
                                                  float* __restrict__ Z1) {
  const int wid = threadIdx.x >> 6, lane = threadIdx.x & 63;
  const int grow = blockIdx.x * 4 + wid;
  const int set = grow >> 10;
  const int row = grow & 1023;
  const float* X = set ? X1 : X0;
  const float* Y = set ? Y1 : Y0;
  const float* g = set ? G1 : G0;
  const float* bb = set ? B1 : B0;
  float* Z = set ? Z1 : Z0;
  const int jb = lane * 4;
  const float4 x4 = *reinterpret_cast<const float4*>(X + (size_t)row * DM + jb);
  const float4 y4 = *reinterpret_cast<const float4*>(Y + (size_t)row * DM + jb);
  float x[4] = {x4.x + y4.x, x4.y + y4.y, x4.z + y4.z, x4.w + y4.w};
  const float mean = wave_red_sum(x[0] + x[1] + x[2] + x[3]) * (1.f / 256.f);
  float vs = 0.f;
#pragma unroll
  for (int q = 0; q < 4; ++q) { const float d = x[q] - mean; vs += d * d; }
  const float var = wave_red_sum(vs) * (1.f / 256.f);
  const float rstd = 1.f / sqrtf(var + 1e-5f);
  const float4 g4 = *reinterpret_cast<const float4*>(g + jb);
  const float4 b4 = *reinterpret_cast<const float4*>(bb + jb);
  float4 o;
  o.x = (x[0] - mean) * rstd * g4.x + b4.x;
  o.y = (x[1] - mean) * rstd * g4.y + b4.y;
  o.z = (x[2] - mean) * rstd * g4.z + b4.z;
  o.w = (x[3] - mean) * rstd * g4.w + b4.w;
  *reinterpret_cast<float4*>(Z + (size_t)row * DM + jb) = o;
}

// ---------------- residual + LayerNorm block 4 ----------------
__global__ __launch_bounds__(256) void dt_ln4w(const float* __restrict__ know,
                                               const float* __restrict__ Y,
                                               const float* __restrict__ g,
                                               const float* __restrict__ bb,
                                               float* __restrict__ Z) {
  const int wid = threadIdx.x >> 6, lane = threadIdx.x & 63;
  const int row = blockIdx.x * 4 + wid;  // (b*16+nk)*256 + i
  const int i = row & 255;
  const int nk = (row >> 8) & 15;
  const int b = row >> 12;
  const int jb = lane * 4;
  const float4 k4 = *reinterpret_cast<const float4*>(know + (size_t)nk * DM + jb);
  const float4 y4 = *reinterpret_cast<const float4*>(Y + (size_t)row * DM + jb);
  float x[4] = {k4.x + y4.x, k4.y + y4.y, k4.z + y4.z, k4.w + y4.w};
  const float mean = wave_red_sum(x[0] + x[1] + x[2] + x[3]) * (1.f / 256.f);
  float vs = 0.f;
#pragma unroll
  for (int q = 0; q < 4; ++q) { const float d = x[q] - mean; vs += d * d; }
  const float var = wave_red_sum(vs) * (1.f / 256.f);
  const float rstd = 1.f / sqrtf(var + 1e-5f);
  const float4 g4 = *reinterpret_cast<const float4*>(g + jb);
  const float4 b4 = *reinterpret_cast<const float4*>(bb + jb);
  float4 o;
  o.x = (x[0] - mean) * rstd * g4.x + b4.x;
  o.y = (x[1] - mean) * rstd * g4.y + b4.y;
  o.z = (x[2] - mean) * rstd * g4.z + b4.z;
  o.w = (x[3] - mean) * rstd * g4.w + b4.w;
  *reinterpret_cast<float4*>(Z + ((size_t)(b * SEQL + i)) * (NKN * DM) + (size_t)nk * DM + jb) = o;
}

// ---------------- launcher ----------------
extern "C" void kernel_launch(void* const* d_in, const int* in_sizes, int n_in,
                              void* d_out, int out_size, void* d_ws, size_t ws_size,
                              hipStream_t stream) {
  (void)in_sizes; (void)n_in; (void)out_size; (void)ws_size;
  const float* q_emb = (const float*)d_in[0];
  const float* s_emb = (const float*)d_in[1];
  const float* know  = (const float*)d_in[3];
  const float* Wq1 = (const float*)d_in[4],  *bq1 = (const float*)d_in[5];
  const float* Wv1 = (const float*)d_in[6],  *bv1 = (const float*)d_in[7];
  const float* Wo1 = (const float*)d_in[8],  *bo1 = (const float*)d_in[9];
  const float* gam1 = (const float*)d_in[10], *lng1 = (const float*)d_in[11], *lnb1 = (const float*)d_in[12];
  const float* Wq2 = (const float*)d_in[13], *bq2 = (const float*)d_in[14];
  const float* Wv2 = (const float*)d_in[15], *bv2 = (const float*)d_in[16];
  const float* Wo2 = (const float*)d_in[17], *bo2 = (const float*)d_in[18];
  const float* gam2 = (const float*)d_in[19], *lng2 = (const float*)d_in[20], *lnb2 = (const float*)d_in[21];
  const float* Wq3 = (const float*)d_in[22], *bq3 = (const float*)d_in[23];
  const float* Wv3 = (const float*)d_in[24], *bv3 = (const float*)d_in[25];
  const float* Wo3 = (const float*)d_in[26], *bo3 = (const float*)d_in[27];
  const float* gam3 = (const float*)d_in[28], *lng3 = (const float*)d_in[29], *lnb3 = (const float*)d_in[30];
  const float* Wq4 = (const float*)d_in[31], *bq4 = (const float*)d_in[32];
  const float* Wk4 = (const float*)d_in[33], *bk4 = (const float*)d_in[34];
  const float* Wv4 = (const float*)d_in[35], *bv4 = (const float*)d_in[36];
  const float* Wo4 = (const float*)d_in[37], *bo4 = (const float*)d_in[38];
  const float* gam4 = (const float*)d_in[39], *lng4 = (const float*)d_in[40], *lnb4 = (const float*)d_in[41];

  float* ws = (float*)d_ws;
  const size_t U = 262144;
  float* Qp0 = ws + 0 * U;           // also Qp3, Kp4
  float* Qp1 = ws + 1 * U;
  float* Vp0 = ws + 2 * U;           // also Vp3, Vp4
  float* Vp1 = ws + 3 * U;
  float* Sa  = ws + 4 * U;           // 8U; block 4: OW4 (16U)
  float* Sb  = ws + 12 * U;          // 8U
  float* O0  = ws + 20 * U;          // also O3, then Pfx (b4)
  float* O1  = ws + 21 * U;
  float* OW0 = ws + 22 * U;          // also OW3
  float* OW1 = ws + 23 * U;
  float* hq  = ws + 24 * U;
  float* hs  = ws + 25 * U;
  float* pbf = ws + 26 * U;
  float* Q4h = ws + 27 * U;          // 4096
  float* S0s = Q4h + 4096;           // 131072
  float* OW4 = Sa;                   // 16U (Sa..Sb dead in block 4)
  float* Pfx = O0;                   // dead after block-3 out-proj

  float* zout = (float*)d_out;
  float* qsc  = zout + 4194304;
  float* ksc  = qsc + 2097152;
  float* O4   = zout;                // scratch; ln4w fully rewrites zout at the end

  const dim3 thr(256);

  // ---- blocks 1+2 batched ----
  {
    Gemm4 a = {{{q_emb, Wq1, bq1, Qp0, 1024}, {q_emb, Wv1, bv1, Vp0, 1024},
                {s_emb, Wq2, bq2, Qp1, 1024}, {s_emb, Wv2, bv2, Vp1, 1024}}};
    dt_gemm32<<<dim3(32, 4, 4), thr, 0, stream>>>(a);
  }
  dt_scores_nt2<<<dim3(8, 8, 64), thr, 0, stream>>>(Qp0, Qp1, Sa, Sb);
  dt_softmax13w2<<<dim3(4096), thr, 0, stream>>>(Sa, Sb, Sa, Sb, gam1, gam2);
  dt_pv13_2<<<dim3(8, 64), thr, 0, stream>>>(Sa, Sb, Vp0, Vp1, O0, O1);
  {
    Gemm4 a = {{{O0, Wo1, bo1, OW0, 1024}, {O1, Wo2, bo2, OW1, 1024},
                {O0, Wo1, bo1, OW0, 1024}, {O1, Wo2, bo2, OW1, 1024}}};
    dt_gemm32<<<dim3(32, 4, 2), thr, 0, stream>>>(a);
  }
  dt_ln_res2<<<dim3(512), thr, 0, stream>>>(q_emb, s_emb, OW0, OW1, lng1, lng2, lnb1, lnb2, hq, hs);

  // ---- block 3 (q=k=hq, v=hs -> pbf; scores -> q_scores out) ----
  {
    Gemm4 a = {{{hq, Wq3, bq3, Qp0, 1024}, {hs, Wv3, bv3, Vp0, 1024},
                {hq, Wq3, bq3, Qp0, 1024}, {hs, Wv3, bv3, Vp0, 1024}}};
    dt_gemm32<<<dim3(32, 4, 2), thr, 0, stream>>>(a);
  }
  dt_scores_nt2<<<dim3(8, 8, 32), thr, 0, stream>>>(Qp0, Qp0, Sa, Sa);
  dt_softmax13w2<<<dim3(2048), thr, 0, stream>>>(Sa, Sa, qsc, qsc, gam3, gam3);
  dt_pv13_2<<<dim3(8, 32), thr, 0, stream>>>(qsc, qsc, Vp0, Vp0, O0, O0);
  {
    Gemm4 a = {{{O0, Wo3, bo3, OW0, 1024}, {O0, Wo3, bo3, OW0, 1024},
                {O0, Wo3, bo3, OW0, 1024}, {O0, Wo3, bo3, OW0, 1024}}};
    dt_gemm32<<<dim3(32, 4, 1), thr, 0, stream>>>(a);
  }
  dt_ln_res2<<<dim3(256), thr, 0, stream>>>(hq, hq, OW0, OW0, lng3, lng3, lnb3, lnb3, pbf, pbf);

  // ---- block 4 ----
  {
    Gemm4 a = {{{hq, Wk4, bk4, Qp0, 1024}, {pbf, Wv4, bv4, Vp0, 1024},
                {know, Wq4, bq4, Q4h, 16}, {know, Wq4, bq4, Q4h, 16}}};
    dt_gemmN<<<dim3(16, 4, 3), thr, 0, stream>>>(a);
  }
  dt_scores4<<<dim3(512), thr, 0, stream>>>(Q4h, Qp0, S0s);
  dt_prep4<<<dim3(128), thr, 0, stream>>>(S0s, Pfx);
  dt_sm_pv4<<<dim3(2, 512), thr, 0, stream>>>(S0s, Pfx, Vp0, gam4, ksc, O4);
  {
    Gemm4 a = {{{O4, Wo4, bo4, OW4, 16384}, {O4, Wo4, bo4, OW4, 16384},
                {O4, Wo4, bo4, OW4, 16384}, {O4, Wo4, bo4, OW4, 16384}}};
    dt_gemmN<<<dim3(256, 4, 1), thr, 0, stream>>>(a);
  }
  dt_ln4w<<<dim3(4096), thr, 0, stream>>>(know, OW4, lng4, lnb4, zout);
}